// Round 1
// baseline (2586.899 us; speedup 1.0000x reference)
//
#include <hip/hip_runtime.h>
#include <cstdint>
#include <cstddef>

// ---------------- workspace layout (float offsets) ----------------
static constexpr size_t ROI_OFF  = 0;                          // [8][1024][32][32]  NCHW
static constexpr size_t ROI_N    = (size_t)8 * 1024 * 32 * 32; // 8388608
static constexpr size_t PART_OFF = ROI_OFF + ROI_N;            // [4][8*1024][256]   K-split partials
static constexpr size_t PART_N   = (size_t)4 * 8 * 1024 * 256; // 8388608
static constexpr size_t WT1_OFF  = PART_OFF + PART_N;          // [1024][9][256]     conv_w transposed
static constexpr size_t WT1_N    = (size_t)1024 * 9 * 256;
static constexpr size_t WT2_OFF  = WT1_OFF + WT1_N;            // [256][9][256]      mw1 transposed
static constexpr size_t WT2_N    = (size_t)256 * 9 * 256;
static constexpr size_t M2_OFF   = WT2_OFF + WT2_N;            // [8][130][130]      mask pre-resize
static constexpr size_t M2_N     = (size_t)8 * 130 * 130;

// ---------------- weight transpose: OIHW -> [ci][k][co] ----------------
__global__ __launch_bounds__(256) void k_transpose_w(
    const float* __restrict__ conv_w, const float* __restrict__ mw1,
    float* __restrict__ wT1, float* __restrict__ wT2) {
  int stride = gridDim.x * 256;
  int idx = blockIdx.x * 256 + threadIdx.x;
  for (int i = idx; i < 256 * 1024 * 9; i += stride) {
    int co = i / (1024 * 9);
    int r  = i - co * (1024 * 9);
    int ci = r / 9;
    int k  = r - ci * 9;
    wT1[((size_t)ci * 9 + k) * 256 + co] = conv_w[i];
  }
  for (int i = idx; i < 256 * 256 * 9; i += stride) {
    int co = i / (256 * 9);
    int r  = i - co * (256 * 9);
    int ci = r / 9;
    int k  = r - ci * 9;
    wT2[((size_t)ci * 9 + k) * 256 + co] = mw1[i];
  }
}

// ---------------- deform MLP + anchors -> prop ----------------
// block: (b, i, j0..j0+3); 512 blocks x 256 threads
__global__ __launch_bounds__(256) void k_prop(
    const float* __restrict__ o,
    const float* __restrict__ dw1, const float* __restrict__ db1,
    const float* __restrict__ dw2, const float* __restrict__ db2,
    float* __restrict__ prop) {
  __shared__ float o_lds[4 * 768];
  __shared__ float h_lds[4 * 256];
  int t = threadIdx.x;
  int bid = blockIdx.x;
  int b = bid >> 6;
  int rem = bid & 63;
  int i = rem >> 2;
  int j0 = (rem & 3) * 4;
  const float* obase = o + ((size_t)(b * 16 + i) * 16 + j0) * 768;
  for (int e = t; e < 4 * 768; e += 256) o_lds[e] = obase[e];
  __syncthreads();
  float h0 = 0.f, h1 = 0.f, h2 = 0.f, h3 = 0.f;
  for (int k = 0; k < 768; ++k) {
    float w = dw1[k * 256 + t];
    h0 = fmaf(o_lds[k], w, h0);
    h1 = fmaf(o_lds[768 + k], w, h1);
    h2 = fmaf(o_lds[1536 + k], w, h2);
    h3 = fmaf(o_lds[2304 + k], w, h3);
  }
  float bb = db1[t];
  h_lds[t]        = fmaxf(h0 + bb, 0.f);
  h_lds[256 + t]  = fmaxf(h1 + bb, 0.f);
  h_lds[512 + t]  = fmaxf(h2 + bb, 0.f);
  h_lds[768 + t]  = fmaxf(h3 + bb, 0.f);
  __syncthreads();
  if (t < 32) {
    int pos = t >> 3;      // which j within the 4
    int c   = t & 7;       // output channel of the 8
    float acc = db2[c];
    const float* hp = h_lds + pos * 256;
    for (int k = 0; k < 256; ++k) acc = fmaf(hp[k], dw2[k * 8 + c], acc);
    // pixel-shuffle: d[b, 2i+p, 2j+q, cc] = mlp[b,i,j, p*4+q*2+cc]
    int p = c >> 2, q = (c >> 1) & 1, cc = c & 1;
    int row = 2 * i + p;
    int col = 2 * (j0 + pos) + q;
    float anchor = (cc == 0) ? ((float)col * 16.f + 8.f) : ((float)row * 16.f + 8.f);
    prop[((size_t)(b * 32 + row) * 32 + col) * 2 + cc] = anchor + acc;
  }
}

// ---------------- grid sample 4 levels -> roi (NCHW [8][1024][32][32]) ----------------
// block: (py, l, b); threads: xq = t&31 (x position), cq = t>>5 (channel offset)
__global__ __launch_bounds__(256) void k_sample(
    const float* __restrict__ f0, const float* __restrict__ f1,
    const float* __restrict__ f2, const float* __restrict__ f3,
    const float* __restrict__ prop, float* __restrict__ roi) {
  int py = blockIdx.x;
  int l  = blockIdx.y;
  int b  = blockIdx.z;
  int t  = threadIdx.x;
  int xq = t & 31;
  int cq = t >> 5;
  const float* f = (l == 0) ? f0 : (l == 1) ? f1 : (l == 2) ? f2 : f3;
  int fsz = 128 >> l;
  float s = (float)(4 << l);

  size_t pidx = ((size_t)b * 32 + py) * 32 + xq;
  float px = prop[pidx * 2 + 0];
  float pv = prop[pidx * 2 + 1];
  float gx = 2.f * px / s / (float)fsz - 1.f;
  float gy = 2.f * pv / s / (float)fsz - 1.f;
  float x = (gx + 1.f) * 0.5f * (float)(fsz - 1);
  float y = (gy + 1.f) * 0.5f * (float)(fsz - 1);
  float x0f = floorf(x), y0f = floorf(y);
  float wx1 = x - x0f, wy1 = y - y0f;

  int off[4];
  float wgt[4];
#pragma unroll
  for (int cy = 0; cy < 2; ++cy) {
#pragma unroll
    for (int cx = 0; cx < 2; ++cx) {
      float xf = x0f + (float)cx;
      float yf = y0f + (float)cy;
      float w = (cy ? wy1 : (1.f - wy1)) * (cx ? wx1 : (1.f - wx1));
      bool valid = (xf >= 0.f) && (xf <= (float)(fsz - 1)) &&
                   (yf >= 0.f) && (yf <= (float)(fsz - 1));
      int xi = (int)fminf(fmaxf(xf, 0.f), (float)(fsz - 1));
      int yi = (int)fminf(fmaxf(yf, 0.f), (float)(fsz - 1));
      off[cy * 2 + cx] = yi * fsz + xi;
      wgt[cy * 2 + cx] = valid ? w : 0.f;
    }
  }
  const float* fb = f + (size_t)b * 256 * fsz * fsz;
  float* rb = roi + ((size_t)b * 1024 + l * 256) * 1024 + py * 32 + xq;
  for (int c0 = 0; c0 < 256; c0 += 8) {
    int c = c0 + cq;
    const float* fc = fb + (size_t)c * fsz * fsz;
    float acc = wgt[0] * fc[off[0]] + wgt[1] * fc[off[1]] +
                wgt[2] * fc[off[2]] + wgt[3] * fc[off[3]];
    rb[(size_t)c * 1024] = acc;
  }
}

// ---------------- roi 3x3 conv (K-split x4) -> partials [kc][8192][256] ----------------
// block: kc(4) x b(8) x tile(16 of 8x8); 512 blocks
__global__ __launch_bounds__(256) void k_conv_roi(
    const float* __restrict__ roi, const float* __restrict__ wT1,
    float* __restrict__ part) {
  __shared__ float patch[16 * 100];
  int t = threadIdx.x;
  int co_t = t & 31;
  int px_t = t >> 5;  // column within tile
  int bid = blockIdx.x;
  int kc = bid >> 7;
  int rest = bid & 127;
  int b = rest >> 4;
  int tile = rest & 15;
  int ty = (tile >> 2) * 8;
  int tx = (tile & 3) * 8;

  float acc[8][8];
#pragma unroll
  for (int i = 0; i < 8; ++i)
#pragma unroll
    for (int j = 0; j < 8; ++j) acc[i][j] = 0.f;

  for (int ci0 = kc * 256; ci0 < kc * 256 + 256; ci0 += 16) {
    __syncthreads();
    for (int e = t; e < 1600; e += 256) {
      int ci = e / 100;
      int pos = e - ci * 100;
      int yy = pos / 10, xx = pos - yy * 10;
      int gy = ty + yy - 1, gx = tx + xx - 1;
      float v = 0.f;
      if (gy >= 0 && gy < 32 && gx >= 0 && gx < 32)
        v = roi[((size_t)b * 1024 + ci0 + ci) * 1024 + gy * 32 + gx];
      patch[ci * 100 + pos] = v;
    }
    __syncthreads();
    for (int ci = 0; ci < 16; ++ci) {
      for (int k = 0; k < 9; ++k) {
        int ky = k / 3, kx = k - ky * 3;
        const float* wrow = wT1 + ((size_t)(ci0 + ci) * 9 + k) * 256 + co_t;
        float wv[8];
#pragma unroll
        for (int j = 0; j < 8; ++j) wv[j] = wrow[32 * j];
        const float* prow = patch + ci * 100 + ky * 10 + px_t + kx;
#pragma unroll
        for (int i = 0; i < 8; ++i) {
          float iv = prow[i * 10];
#pragma unroll
          for (int j = 0; j < 8; ++j) acc[i][j] = fmaf(iv, wv[j], acc[i][j]);
        }
      }
    }
  }
  float* pb = part + (size_t)kc * (8 * 1024 * 256);
#pragma unroll
  for (int i = 0; i < 8; ++i) {
    int gy = ty + i, gx = tx + px_t;
    size_t pix = ((size_t)b * 32 + gy) * 32 + gx;
#pragma unroll
    for (int j = 0; j < 8; ++j) pb[pix * 256 + co_t + 32 * j] = acc[i][j];
  }
}

// ---------------- per-pixel classifier MLP (4 pixels/block) ----------------
__global__ __launch_bounds__(256) void k_mlp(
    const float* __restrict__ part, const float* __restrict__ conv_b,
    const float* __restrict__ cw1, const float* __restrict__ cb1,
    const float* __restrict__ cw2, const float* __restrict__ cb2,
    float* __restrict__ logits) {
  __shared__ float v[1024];
  __shared__ float h[1024];
  int t = threadIdx.x;
  size_t base = (size_t)blockIdx.x * 1024;
  const size_t CH = (size_t)8 * 1024 * 256;
  for (int e = t; e < 1024; e += 256) {
    float s = part[base + e] + part[CH + base + e] +
              part[2 * CH + base + e] + part[3 * CH + base + e];
    v[e] = s + conv_b[e & 255];
  }
  __syncthreads();
  float a0 = cb1[t], a1 = a0, a2 = a0, a3 = a0;
  for (int k = 0; k < 256; ++k) {
    float w = cw1[k * 256 + t];
    a0 = fmaf(v[k], w, a0);
    a1 = fmaf(v[256 + k], w, a1);
    a2 = fmaf(v[512 + k], w, a2);
    a3 = fmaf(v[768 + k], w, a3);
  }
  h[t]       = fmaxf(a0, 0.f);
  h[256 + t] = fmaxf(a1, 0.f);
  h[512 + t] = fmaxf(a2, 0.f);
  h[768 + t] = fmaxf(a3, 0.f);
  __syncthreads();
  if (t < 24) {
    int pos = t / 6, c = t - 6 * pos;
    float acc = cb2[c];
    const float* hp = h + pos * 256;
    for (int k = 0; k < 256; ++k) acc = fmaf(hp[k], cw2[k * 6 + c], acc);
    logits[((size_t)blockIdx.x * 4 + pos) * 6 + c] = acc;
  }
}

// ---------------- m2 init (border = mb2) ----------------
__global__ __launch_bounds__(256) void k_m2_init(const float* __restrict__ mb2,
                                                 float* __restrict__ m2) {
  int i = blockIdx.x * 256 + threadIdx.x;
  if (i < (int)M2_N) m2[i] = mb2[0];
}

// ---------------- fused mask head: conv3x3 + BN + ReLU + 1x1 -> m2 interior ----------------
// block: b(8) x tile(256 of 8x8 on 128x128); 2048 blocks
__global__ __launch_bounds__(256) void k_mask_conv(
    const float* __restrict__ mf, const float* __restrict__ wT2,
    const float* __restrict__ mb1,
    const float* __restrict__ bn_g, const float* __restrict__ bn_b,
    const float* __restrict__ bn_m, const float* __restrict__ bn_v,
    const float* __restrict__ mw2, const float* __restrict__ mb2,
    float* __restrict__ m2) {
  __shared__ float patch[16 * 100];
  __shared__ float red[64][33];
  int t = threadIdx.x;
  int co_t = t & 31;
  int px_t = t >> 5;
  int bid = blockIdx.x;
  int b = bid >> 8;
  int tile = bid & 255;
  int ty = (tile >> 4) * 8;
  int tx = (tile & 15) * 8;

  float acc[8][8];
#pragma unroll
  for (int i = 0; i < 8; ++i)
#pragma unroll
    for (int j = 0; j < 8; ++j) acc[i][j] = 0.f;

  for (int ci0 = 0; ci0 < 256; ci0 += 16) {
    __syncthreads();
    for (int e = t; e < 1600; e += 256) {
      int ci = e / 100;
      int pos = e - ci * 100;
      int yy = pos / 10, xx = pos - yy * 10;
      int gy = ty + yy - 1, gx = tx + xx - 1;
      float v = 0.f;
      if (gy >= 0 && gy < 128 && gx >= 0 && gx < 128)
        v = mf[((size_t)b * 256 + ci0 + ci) * 16384 + gy * 128 + gx];
      patch[ci * 100 + pos] = v;
    }
    __syncthreads();
    for (int ci = 0; ci < 16; ++ci) {
      for (int k = 0; k < 9; ++k) {
        int ky = k / 3, kx = k - ky * 3;
        const float* wrow = wT2 + ((size_t)(ci0 + ci) * 9 + k) * 256 + co_t;
        float wv[8];
#pragma unroll
        for (int j = 0; j < 8; ++j) wv[j] = wrow[32 * j];
        const float* prow = patch + ci * 100 + ky * 10 + px_t + kx;
#pragma unroll
        for (int i = 0; i < 8; ++i) {
          float iv = prow[i * 10];
#pragma unroll
          for (int j = 0; j < 8; ++j) acc[i][j] = fmaf(iv, wv[j], acc[i][j]);
        }
      }
    }
  }
  // epilogue: +mb1, BN(eval), ReLU, dot with mw2 (partial over this thread's 8 co)
  float part_px[8];
#pragma unroll
  for (int i = 0; i < 8; ++i) part_px[i] = 0.f;
#pragma unroll
  for (int j = 0; j < 8; ++j) {
    int co = co_t + 32 * j;
    float sc = bn_g[co] * rsqrtf(bn_v[co] + 1e-5f);
    float sh = bn_b[co] - bn_m[co] * sc;
    float bias = mb1[co];
    float w2 = mw2[co];
#pragma unroll
    for (int i = 0; i < 8; ++i) {
      float z = fmaf(acc[i][j] + bias, sc, sh);
      part_px[i] = fmaf(w2, fmaxf(z, 0.f), part_px[i]);
    }
  }
#pragma unroll
  for (int i = 0; i < 8; ++i) red[i * 8 + px_t][co_t] = part_px[i];
  __syncthreads();
  if (t < 64) {
    float sum = mb2[0];
#pragma unroll
    for (int k = 0; k < 32; ++k) sum += red[t][k];
    int gy = ty + (t >> 3), gx = tx + (t & 7);
    m2[((size_t)b * 130 + gy + 1) * 130 + gx + 1] = sum;
  }
}

// ---------------- align-corners bilinear resize 130x130 -> 512x512 ----------------
__global__ __launch_bounds__(256) void k_resize(const float* __restrict__ m2,
                                                float* __restrict__ masks) {
  int idx = blockIdx.x * 256 + threadIdx.x;  // 0 .. 8*512*512-1 (exact)
  int b = idx >> 18;
  int rem = idx & 262143;
  int y = rem >> 9;
  int x = rem & 511;
  const float SC = 129.0f / 511.0f;
  float sy = (float)y * SC;
  float sx = (float)x * SC;
  float y0f = floorf(sy), x0f = floorf(sx);
  int y0 = (int)y0f, x0 = (int)x0f;
  int y1 = min(y0 + 1, 129), x1 = min(x0 + 1, 129);
  float wy = sy - y0f, wx = sx - x0f;
  const float* mb = m2 + (size_t)b * 130 * 130;
  float top = mb[y0 * 130 + x0] * (1.f - wx) + mb[y0 * 130 + x1] * wx;
  float bot = mb[y1 * 130 + x0] * (1.f - wx) + mb[y1 * 130 + x1] * wx;
  masks[idx] = top * (1.f - wy) + bot * wy;
}

extern "C" void kernel_launch(void* const* d_in, const int* in_sizes, int n_in,
                              void* d_out, int out_size, void* d_ws, size_t ws_size,
                              hipStream_t stream) {
  (void)in_sizes; (void)n_in; (void)out_size; (void)ws_size;
  const float* f0        = (const float*)d_in[1];
  const float* f1        = (const float*)d_in[2];
  const float* f2        = (const float*)d_in[3];
  const float* f3        = (const float*)d_in[4];
  const float* mask_feat = (const float*)d_in[5];
  const float* o         = (const float*)d_in[6];
  const float* dw1       = (const float*)d_in[7];
  const float* db1       = (const float*)d_in[8];
  const float* dw2       = (const float*)d_in[9];
  const float* db2       = (const float*)d_in[10];
  const float* cw1       = (const float*)d_in[11];
  const float* cb1       = (const float*)d_in[12];
  const float* cw2       = (const float*)d_in[13];
  const float* cb2       = (const float*)d_in[14];
  const float* conv_w    = (const float*)d_in[15];
  const float* conv_b    = (const float*)d_in[16];
  const float* mw1       = (const float*)d_in[17];
  const float* mb1       = (const float*)d_in[18];
  const float* bn_g      = (const float*)d_in[19];
  const float* bn_b      = (const float*)d_in[20];
  const float* bn_m      = (const float*)d_in[21];
  const float* bn_v      = (const float*)d_in[22];
  const float* mw2       = (const float*)d_in[23];
  const float* mb2       = (const float*)d_in[24];

  float* ws   = (float*)d_ws;
  float* roi  = ws + ROI_OFF;
  float* part = ws + PART_OFF;
  float* wT1  = ws + WT1_OFF;
  float* wT2  = ws + WT2_OFF;
  float* m2   = ws + M2_OFF;

  float* out_prop   = (float*)d_out;
  float* out_logits = out_prop + (size_t)8 * 1024 * 2;
  float* out_masks  = out_logits + (size_t)8 * 1024 * 6;

  hipLaunchKernelGGL(k_transpose_w, dim3(1024), dim3(256), 0, stream,
                     conv_w, mw1, wT1, wT2);
  hipLaunchKernelGGL(k_prop, dim3(512), dim3(256), 0, stream,
                     o, dw1, db1, dw2, db2, out_prop);
  hipLaunchKernelGGL(k_sample, dim3(32, 4, 8), dim3(256), 0, stream,
                     f0, f1, f2, f3, out_prop, roi);
  hipLaunchKernelGGL(k_conv_roi, dim3(512), dim3(256), 0, stream,
                     roi, wT1, part);
  hipLaunchKernelGGL(k_mlp, dim3(2048), dim3(256), 0, stream,
                     part, conv_b, cw1, cb1, cw2, cb2, out_logits);
  hipLaunchKernelGGL(k_m2_init, dim3((int)((M2_N + 255) / 256)), dim3(256), 0, stream,
                     mb2, m2);
  hipLaunchKernelGGL(k_mask_conv, dim3(2048), dim3(256), 0, stream,
                     mask_feat, wT2, mb1, bn_g, bn_b, bn_m, bn_v, mw2, mb2, m2);
  hipLaunchKernelGGL(k_resize, dim3(8192), dim3(256), 0, stream,
                     m2, out_masks);
}

// Round 2
// 439.050 us; speedup vs baseline: 5.8920x; 5.8920x over previous
//
#include <hip/hip_runtime.h>
#include <cstdint>
#include <cstddef>

using bf16x8 = __attribute__((ext_vector_type(8))) short;
using f32x4  = __attribute__((ext_vector_type(4))) float;

// ---------------- workspace layout (float offsets) ----------------
static constexpr size_t ROI_OFF  = 0;                          // [8][1024][32][32] f32
static constexpr size_t ROI_N    = (size_t)8 * 1024 * 32 * 32; // 8388608
static constexpr size_t PART_OFF = ROI_OFF + ROI_N;            // [4][8192][256] f32 K-split partials
static constexpr size_t PART_N   = (size_t)4 * 8192 * 256;     // 8388608
static constexpr size_t WT_OFF   = PART_OFF + PART_N;          // bf16 region (shorts)
static constexpr size_t WTR_SH   = (size_t)9 * 1024 * 256;     // 2359296 shorts [tap][kcg32][co][ci32]
static constexpr size_t WTM_SH   = (size_t)9 * 256 * 256;      // 589824 shorts  [tap][kc8][co][ci32]
static constexpr size_t M2P_OFF  = WT_OFF + (WTR_SH + WTM_SH) / 2; // [2][8][130][130] f32
static constexpr size_t M2P_N    = (size_t)2 * 8 * 130 * 130;

__device__ __forceinline__ unsigned short f2bf(float f) {
  union { float f; uint32_t u; } c; c.f = f;
  uint32_t u = c.u;
  return (unsigned short)((u + 0x7fffu + ((u >> 16) & 1u)) >> 16);
}

__device__ __forceinline__ void gld16(const void* g, void* l) {
  __builtin_amdgcn_global_load_lds(
      (const __attribute__((address_space(1))) void*)g,
      (__attribute__((address_space(3))) void*)l, 16, 0, 0);
}

// ---------------- weight prep: f32 OIHW -> bf16 [tap][ci/32][co][ci%32] ----------------
__global__ __launch_bounds__(256) void k_prep_w(
    const float* __restrict__ conv_w, const float* __restrict__ mw1,
    short* __restrict__ wTr, short* __restrict__ wTm) {
  int stride = gridDim.x * 256;
  for (int d = blockIdx.x * 256 + threadIdx.x; d < 2359296; d += stride) {
    int tap = d / 262144;               // 262144 = 32*256*32
    int rem = d - tap * 262144;
    int kcg = rem >> 13;                // /8192
    int rem2 = rem & 8191;
    int co = rem2 >> 5;
    int ci = kcg * 32 + (rem2 & 31);
    wTr[d] = (short)f2bf(conv_w[(size_t)(co * 1024 + ci) * 9 + tap]);
  }
  for (int d = blockIdx.x * 256 + threadIdx.x; d < 589824; d += stride) {
    int tap = d >> 16;                  // /65536 = 8*256*32
    int rem = d & 65535;
    int kc = rem >> 13;
    int rem2 = rem & 8191;
    int co = rem2 >> 5;
    int ci = kc * 32 + (rem2 & 31);
    wTm[d] = (short)f2bf(mw1[(size_t)(co * 256 + ci) * 9 + tap]);
  }
}

// ---------------- deform MLP + anchors -> prop ----------------
__global__ __launch_bounds__(256) void k_prop(
    const float* __restrict__ o,
    const float* __restrict__ dw1, const float* __restrict__ db1,
    const float* __restrict__ dw2, const float* __restrict__ db2,
    float* __restrict__ prop) {
  __shared__ float o_lds[4 * 768];
  __shared__ float h_lds[4 * 256];
  int t = threadIdx.x;
  int bid = blockIdx.x;
  int b = bid >> 6;
  int rem = bid & 63;
  int i = rem >> 2;
  int j0 = (rem & 3) * 4;
  const float* obase = o + ((size_t)(b * 16 + i) * 16 + j0) * 768;
  for (int e = t; e < 4 * 768; e += 256) o_lds[e] = obase[e];
  __syncthreads();
  float h0 = 0.f, h1 = 0.f, h2 = 0.f, h3 = 0.f;
  for (int k = 0; k < 768; ++k) {
    float w = dw1[k * 256 + t];
    h0 = fmaf(o_lds[k], w, h0);
    h1 = fmaf(o_lds[768 + k], w, h1);
    h2 = fmaf(o_lds[1536 + k], w, h2);
    h3 = fmaf(o_lds[2304 + k], w, h3);
  }
  float bb = db1[t];
  h_lds[t]        = fmaxf(h0 + bb, 0.f);
  h_lds[256 + t]  = fmaxf(h1 + bb, 0.f);
  h_lds[512 + t]  = fmaxf(h2 + bb, 0.f);
  h_lds[768 + t]  = fmaxf(h3 + bb, 0.f);
  __syncthreads();
  if (t < 32) {
    int pos = t >> 3;
    int c   = t & 7;
    float acc = db2[c];
    const float* hp = h_lds + pos * 256;
    for (int k = 0; k < 256; ++k) acc = fmaf(hp[k], dw2[k * 8 + c], acc);
    int p = c >> 2, q = (c >> 1) & 1, cc = c & 1;
    int row = 2 * i + p;
    int col = 2 * (j0 + pos) + q;
    float anchor = (cc == 0) ? ((float)col * 16.f + 8.f) : ((float)row * 16.f + 8.f);
    prop[((size_t)(b * 32 + row) * 32 + col) * 2 + cc] = anchor + acc;
  }
}

// ---------------- grid sample 4 levels -> roi (NCHW [8][1024][32][32]) ----------------
__global__ __launch_bounds__(256) void k_sample(
    const float* __restrict__ f0, const float* __restrict__ f1,
    const float* __restrict__ f2, const float* __restrict__ f3,
    const float* __restrict__ prop, float* __restrict__ roi) {
  int py = blockIdx.x;
  int l  = blockIdx.y;
  int b  = blockIdx.z;
  int t  = threadIdx.x;
  int xq = t & 31;
  int cq = t >> 5;
  const float* f = (l == 0) ? f0 : (l == 1) ? f1 : (l == 2) ? f2 : f3;
  int fsz = 128 >> l;
  float s = (float)(4 << l);

  size_t pidx = ((size_t)b * 32 + py) * 32 + xq;
  float px = prop[pidx * 2 + 0];
  float pv = prop[pidx * 2 + 1];
  float gx = 2.f * px / s / (float)fsz - 1.f;
  float gy = 2.f * pv / s / (float)fsz - 1.f;
  float x = (gx + 1.f) * 0.5f * (float)(fsz - 1);
  float y = (gy + 1.f) * 0.5f * (float)(fsz - 1);
  float x0f = floorf(x), y0f = floorf(y);
  float wx1 = x - x0f, wy1 = y - y0f;

  int off[4];
  float wgt[4];
#pragma unroll
  for (int cy = 0; cy < 2; ++cy) {
#pragma unroll
    for (int cx = 0; cx < 2; ++cx) {
      float xf = x0f + (float)cx;
      float yf = y0f + (float)cy;
      float w = (cy ? wy1 : (1.f - wy1)) * (cx ? wx1 : (1.f - wx1));
      bool valid = (xf >= 0.f) && (xf <= (float)(fsz - 1)) &&
                   (yf >= 0.f) && (yf <= (float)(fsz - 1));
      int xi = (int)fminf(fmaxf(xf, 0.f), (float)(fsz - 1));
      int yi = (int)fminf(fmaxf(yf, 0.f), (float)(fsz - 1));
      off[cy * 2 + cx] = yi * fsz + xi;
      wgt[cy * 2 + cx] = valid ? w : 0.f;
    }
  }
  const float* fb = f + (size_t)b * 256 * fsz * fsz;
  float* rb = roi + ((size_t)b * 1024 + l * 256) * 1024 + py * 32 + xq;
  for (int c0 = 0; c0 < 256; c0 += 8) {
    int c = c0 + cq;
    const float* fc = fb + (size_t)c * fsz * fsz;
    float acc = wgt[0] * fc[off[0]] + wgt[1] * fc[off[1]] +
                wgt[2] * fc[off[2]] + wgt[3] * fc[off[3]];
    rb[(size_t)c * 1024] = acc;
  }
}

// ---------------- ROI 3x3 conv, bf16 MFMA, K-split x4 ----------------
// 256 blocks x 512 thr; tile 256px(8 rows of 32) x 128co; 8 waves 4Mx2N
__global__ __launch_bounds__(512) void k_roi_mfma(
    const float* __restrict__ roi, const short* __restrict__ wTr,
    float* __restrict__ part) {
  __shared__ short A_s[10880];   // [10 rows][34 x][32 ci], 16B-chunk XOR swizzle
  __shared__ short B_s[36864];   // [9 tap][128 co][32 ci] linear
  int t = threadIdx.x;
  int lane = t & 63, wv = t >> 6, wm = wv >> 1, wn = wv & 1;
  int kg = lane >> 4, lr = lane & 15;
  int bid = blockIdx.x;
  int nb = bid & 1;
  int mi = (bid >> 1) & 31;
  int b = mi >> 2, yt = mi & 3;
  int ks = bid >> 6;

  f32x4 acc[4][4];
#pragma unroll
  for (int m = 0; m < 4; ++m)
#pragma unroll
    for (int n = 0; n < 4; ++n) acc[m][n] = {0.f, 0.f, 0.f, 0.f};

  for (int kc = 0; kc < 8; ++kc) {
    // stage A: 10 rows x 34 x 32ci -> 1360 16B chunks
    for (int e = t; e < 1360; e += 512) {
      int px = e % 340;
      int cg = e / 340;
      int r = px / 34;
      int x = px - r * 34 - 1;
      int y = yt * 8 + r - 1;
      bool ok = (x >= 0) && (x < 32) && (y >= 0) && (y < 32);
      const float* src = roi + (((size_t)(b * 1024 + ks * 256 + kc * 32 + cg * 8)) << 10)
                             + y * 32 + x;
      float v[8];
#pragma unroll
      for (int j = 0; j < 8; ++j) v[j] = ok ? src[j << 10] : 0.f;
      uint32_t q0 = f2bf(v[0]) | ((uint32_t)f2bf(v[1]) << 16);
      uint32_t q1 = f2bf(v[2]) | ((uint32_t)f2bf(v[3]) << 16);
      uint32_t q2 = f2bf(v[4]) | ((uint32_t)f2bf(v[5]) << 16);
      uint32_t q3 = f2bf(v[6]) | ((uint32_t)f2bf(v[7]) << 16);
      uint4 pk = make_uint4(q0, q1, q2, q3);
      *(uint4*)&A_s[px * 32 + ((cg ^ (px & 3)) << 3)] = pk;
    }
    // stage B: 72 x 1KB global_load_lds
    for (int e2 = wv; e2 < 72; e2 += 8) {
      int tap = e2 >> 3, j = e2 & 7;
      const short* g = wTr + ((size_t)((tap * 32 + ks * 8 + kc) * 256 + nb * 128 + j * 16)) * 32
                          + lane * 8;
      gld16(g, &B_s[e2 * 512]);
    }
    __syncthreads();
    for (int ky = 0; ky < 3; ++ky) {
      for (int kx = 0; kx < 3; ++kx) {
        int tap = ky * 3 + kx;
        bf16x8 bfr[4];
#pragma unroll
        for (int n = 0; n < 4; ++n)
          bfr[n] = *(const bf16x8*)&B_s[(tap * 128 + wn * 64 + n * 16 + lr) * 32 + kg * 8];
#pragma unroll
        for (int m = 0; m < 4; ++m) {
          int pb = wm * 64 + m * 16;
          int px = ((pb >> 5) + ky) * 34 + (pb & 31) + lr + kx;
          bf16x8 af = *(const bf16x8*)&A_s[px * 32 + ((kg ^ (px & 3)) << 3)];
#pragma unroll
          for (int n = 0; n < 4; ++n)
            acc[m][n] = __builtin_amdgcn_mfma_f32_16x16x32_bf16(af, bfr[n], acc[m][n], 0, 0, 0);
        }
      }
    }
    __syncthreads();
  }
  // epilogue: raw f32 partial stores
#pragma unroll
  for (int m = 0; m < 4; ++m)
#pragma unroll
    for (int r = 0; r < 4; ++r) {
      int p = wm * 64 + m * 16 + kg * 4 + r;
      int y = yt * 8 + (p >> 5), x = p & 31;
      float* dst = part + (size_t)ks * 2097152 + (((size_t)b * 32 + y) * 32 + x) * 256
                        + nb * 128 + wn * 64 + lr;
#pragma unroll
      for (int n = 0; n < 4; ++n) dst[n * 16] = acc[m][n][r];
    }
}

// ---------------- per-pixel classifier MLP (4 pixels/block) ----------------
__global__ __launch_bounds__(256) void k_mlp(
    const float* __restrict__ part, const float* __restrict__ conv_b,
    const float* __restrict__ cw1, const float* __restrict__ cb1,
    const float* __restrict__ cw2, const float* __restrict__ cb2,
    float* __restrict__ logits) {
  __shared__ float v[1024];
  __shared__ float h[1024];
  int t = threadIdx.x;
  size_t base = (size_t)blockIdx.x * 1024;
  const size_t CH = (size_t)8192 * 256;
  for (int e = t; e < 1024; e += 256) {
    float s = part[base + e] + part[CH + base + e] +
              part[2 * CH + base + e] + part[3 * CH + base + e];
    v[e] = s + conv_b[e & 255];
  }
  __syncthreads();
  float a0 = cb1[t], a1 = a0, a2 = a0, a3 = a0;
  for (int k = 0; k < 256; ++k) {
    float w = cw1[k * 256 + t];
    a0 = fmaf(v[k], w, a0);
    a1 = fmaf(v[256 + k], w, a1);
    a2 = fmaf(v[512 + k], w, a2);
    a3 = fmaf(v[768 + k], w, a3);
  }
  h[t]       = fmaxf(a0, 0.f);
  h[256 + t] = fmaxf(a1, 0.f);
  h[512 + t] = fmaxf(a2, 0.f);
  h[768 + t] = fmaxf(a3, 0.f);
  __syncthreads();
  if (t < 24) {
    int pos = t / 6, c = t - 6 * pos;
    float acc = cb2[c];
    const float* hp = h + pos * 256;
    for (int k = 0; k < 256; ++k) acc = fmaf(hp[k], cw2[k * 6 + c], acc);
    logits[((size_t)blockIdx.x * 4 + pos) * 6 + c] = acc;
  }
}

// ---------------- mask head: bf16 MFMA conv3x3 + BN + ReLU + 1x1 partials ----------------
// 1024 blocks x 512 thr; tile 256px(2 rows of 128) x 128co; 8 waves 4Mx2N
__global__ __launch_bounds__(512) void k_mask_mfma(
    const float* __restrict__ mf, const short* __restrict__ wTm,
    const float* __restrict__ mb1,
    const float* __restrict__ bn_g, const float* __restrict__ bn_b,
    const float* __restrict__ bn_m, const float* __restrict__ bn_v,
    const float* __restrict__ mw2, float* __restrict__ m2p) {
  __shared__ short A_s[16640];   // [4 rows][130 x][32 ci], 16B-chunk XOR swizzle
  __shared__ short B_s[36864];   // [9 tap][128 co][32 ci] linear
  int t = threadIdx.x;
  int lane = t & 63, wv = t >> 6, wm = wv >> 1, wn = wv & 1;
  int kg = lane >> 4, lr = lane & 15;
  int bid = blockIdx.x;
  int nb = bid & 1;
  int mi = bid >> 1;
  int b = mi >> 6, yt = mi & 63;

  f32x4 acc[4][4];
#pragma unroll
  for (int m = 0; m < 4; ++m)
#pragma unroll
    for (int n = 0; n < 4; ++n) acc[m][n] = {0.f, 0.f, 0.f, 0.f};

  for (int kc = 0; kc < 8; ++kc) {
    // stage A: 4 rows x 130 x 32ci -> 2080 16B chunks
    for (int e = t; e < 2080; e += 512) {
      int px = e % 520;
      int cg = e / 520;
      int r = px / 130;
      int x = px - r * 130 - 1;
      int y = 2 * yt + r - 1;
      bool ok = (x >= 0) && (x < 128) && (y >= 0) && (y < 128);
      const float* src = mf + (((size_t)(b * 256 + kc * 32 + cg * 8)) << 14) + y * 128 + x;
      float v[8];
#pragma unroll
      for (int j = 0; j < 8; ++j) v[j] = ok ? src[j << 14] : 0.f;
      uint32_t q0 = f2bf(v[0]) | ((uint32_t)f2bf(v[1]) << 16);
      uint32_t q1 = f2bf(v[2]) | ((uint32_t)f2bf(v[3]) << 16);
      uint32_t q2 = f2bf(v[4]) | ((uint32_t)f2bf(v[5]) << 16);
      uint32_t q3 = f2bf(v[6]) | ((uint32_t)f2bf(v[7]) << 16);
      uint4 pk = make_uint4(q0, q1, q2, q3);
      *(uint4*)&A_s[px * 32 + ((cg ^ (px & 3)) << 3)] = pk;
    }
    // stage B
    for (int e2 = wv; e2 < 72; e2 += 8) {
      int tap = e2 >> 3, j = e2 & 7;
      const short* g = wTm + ((size_t)((tap * 8 + kc) * 256 + nb * 128 + j * 16)) * 32
                          + lane * 8;
      gld16(g, &B_s[e2 * 512]);
    }
    __syncthreads();
    for (int ky = 0; ky < 3; ++ky) {
      for (int kx = 0; kx < 3; ++kx) {
        int tap = ky * 3 + kx;
        bf16x8 bfr[4];
#pragma unroll
        for (int n = 0; n < 4; ++n)
          bfr[n] = *(const bf16x8*)&B_s[(tap * 128 + wn * 64 + n * 16 + lr) * 32 + kg * 8];
#pragma unroll
        for (int m = 0; m < 4; ++m) {
          int px = ((wm >> 1) + ky) * 130 + (wm & 1) * 64 + m * 16 + lr + kx;
          bf16x8 af = *(const bf16x8*)&A_s[px * 32 + ((kg ^ (px & 3)) << 3)];
#pragma unroll
          for (int n = 0; n < 4; ++n)
            acc[m][n] = __builtin_amdgcn_mfma_f32_16x16x32_bf16(af, bfr[n], acc[m][n], 0, 0, 0);
        }
      }
    }
    __syncthreads();
  }
  // epilogue: bias + BN + ReLU + 1x1 partial reduce over this block's 128 co
  float sc[4], sh[4], w2v[4], b1[4];
#pragma unroll
  for (int n = 0; n < 4; ++n) {
    int co = nb * 128 + wn * 64 + n * 16 + lr;
    float s = bn_g[co] * rsqrtf(bn_v[co] + 1e-5f);
    sc[n] = s;
    sh[n] = bn_b[co] - bn_m[co] * s;
    b1[n] = mb1[co];
    w2v[n] = mw2[co];
  }
  float* red = (float*)B_s;   // [2 wn][256 px][16 lr]
#pragma unroll
  for (int m = 0; m < 4; ++m)
#pragma unroll
    for (int r = 0; r < 4; ++r) {
      int p = wm * 64 + m * 16 + kg * 4 + r;
      float s = 0.f;
#pragma unroll
      for (int n = 0; n < 4; ++n) {
        float z = fmaf(acc[m][n][r] + b1[n], sc[n], sh[n]);
        s = fmaf(w2v[n], fmaxf(z, 0.f), s);
      }
      red[(wn * 256 + p) * 16 + lr] = s;
    }
  __syncthreads();
  if (t < 256) {
    float s = 0.f;
#pragma unroll
    for (int q = 0; q < 16; ++q) s += red[t * 16 + q] + red[(256 + t) * 16 + q];
    int y = 2 * yt + (t >> 7);
    int x = t & 127;
    m2p[((size_t)(nb * 8 + b) * 130 + y + 1) * 130 + x + 1] = s;
  }
}

// ---------------- resize 130x130 -> 512x512 (combines co-half partials + mb2) ----------------
__global__ __launch_bounds__(256) void k_resize(const float* __restrict__ m2p,
                                                const float* __restrict__ mb2,
                                                float* __restrict__ masks) {
  int idx = blockIdx.x * 256 + threadIdx.x;
  int b = idx >> 18;
  int rem = idx & 262143;
  int y = rem >> 9;
  int x = rem & 511;
  const float SC = 129.0f / 511.0f;
  float sy = (float)y * SC;
  float sx = (float)x * SC;
  float y0f = floorf(sy), x0f = floorf(sx);
  int y0 = (int)y0f, x0 = (int)x0f;
  int y1 = min(y0 + 1, 129), x1 = min(x0 + 1, 129);
  float wy = sy - y0f, wx = sx - x0f;
  float base = mb2[0];
  const float* p0 = m2p + (size_t)b * 16900;
  const float* p1 = m2p + 135200 + (size_t)b * 16900;

  auto corner = [&](int yy, int xx) -> float {
    if (yy >= 1 && yy <= 128 && xx >= 1 && xx <= 128) {
      int o2 = yy * 130 + xx;
      return base + p0[o2] + p1[o2];
    }
    return base;
  };
  float tv = corner(y0, x0) * (1.f - wx) + corner(y0, x1) * wx;
  float bv = corner(y1, x0) * (1.f - wx) + corner(y1, x1) * wx;
  masks[idx] = tv * (1.f - wy) + bv * wy;
}

extern "C" void kernel_launch(void* const* d_in, const int* in_sizes, int n_in,
                              void* d_out, int out_size, void* d_ws, size_t ws_size,
                              hipStream_t stream) {
  (void)in_sizes; (void)n_in; (void)out_size; (void)ws_size;
  const float* f0        = (const float*)d_in[1];
  const float* f1        = (const float*)d_in[2];
  const float* f2        = (const float*)d_in[3];
  const float* f3        = (const float*)d_in[4];
  const float* mask_feat = (const float*)d_in[5];
  const float* o         = (const float*)d_in[6];
  const float* dw1       = (const float*)d_in[7];
  const float* db1       = (const float*)d_in[8];
  const float* dw2       = (const float*)d_in[9];
  const float* db2       = (const float*)d_in[10];
  const float* cw1       = (const float*)d_in[11];
  const float* cb1       = (const float*)d_in[12];
  const float* cw2       = (const float*)d_in[13];
  const float* cb2       = (const float*)d_in[14];
  const float* conv_w    = (const float*)d_in[15];
  const float* conv_b    = (const float*)d_in[16];
  const float* mw1       = (const float*)d_in[17];
  const float* mb1       = (const float*)d_in[18];
  const float* bn_g      = (const float*)d_in[19];
  const float* bn_b      = (const float*)d_in[20];
  const float* bn_m      = (const float*)d_in[21];
  const float* bn_v      = (const float*)d_in[22];
  const float* mw2       = (const float*)d_in[23];
  const float* mb2       = (const float*)d_in[24];

  float* ws   = (float*)d_ws;
  float* roi  = ws + ROI_OFF;
  float* part = ws + PART_OFF;
  short* wTr  = (short*)(ws + WT_OFF);
  short* wTm  = wTr + WTR_SH;
  float* m2p  = ws + M2P_OFF;

  float* out_prop   = (float*)d_out;
  float* out_logits = out_prop + (size_t)8 * 1024 * 2;
  float* out_masks  = out_logits + (size_t)8 * 1024 * 6;

  hipLaunchKernelGGL(k_prep_w, dim3(2048), dim3(256), 0, stream,
                     conv_w, mw1, wTr, wTm);
  hipLaunchKernelGGL(k_prop, dim3(512), dim3(256), 0, stream,
                     o, dw1, db1, dw2, db2, out_prop);
  hipLaunchKernelGGL(k_sample, dim3(32, 4, 8), dim3(256), 0, stream,
                     f0, f1, f2, f3, out_prop, roi);
  hipLaunchKernelGGL(k_roi_mfma, dim3(256), dim3(512), 0, stream,
                     roi, wTr, part);
  hipLaunchKernelGGL(k_mlp, dim3(2048), dim3(256), 0, stream,
                     part, conv_b, cw1, cb1, cw2, cb2, out_logits);
  hipLaunchKernelGGL(k_mask_mfma, dim3(1024), dim3(512), 0, stream,
                     mask_feat, wTm, mb1, bn_g, bn_b, bn_m, bn_v, mw2, m2p);
  hipLaunchKernelGGL(k_resize, dim3(8192), dim3(256), 0, stream,
                     m2p, mb2, out_masks);
}